// Round 1
// 3572.612 us; speedup vs baseline: 2.8166x; 2.8166x over previous
//
#include <hip/hip_runtime.h>
#include <hip/hip_fp16.h>
#include <math.h>

#define S_ 1024
#define D_ 1024
#define H_ 16
#define KV_ 4
#define HD_ 64
#define FF_ 4096
#define V_ 50257
#define L_ 8
#define EPS_ 1.1920929e-7f

using short8 = __attribute__((ext_vector_type(8))) short;
using floatx4 = __attribute__((ext_vector_type(4))) float;

__device__ __forceinline__ unsigned short f2bf(float f) {
  union { float f; unsigned int u; } v; v.f = f;
  unsigned int u = v.u;
  u += 0x7FFFu + ((u >> 16) & 1u);
  return (unsigned short)(u >> 16);
}

__device__ __forceinline__ float fquant(float w, float clip, float scale, float s16) {
  float c = fminf(fmaxf(w, -clip), clip);
  float q = rintf(c / scale);
  q = fminf(fmaxf(q, -127.0f), 127.0f);
  return q * s16;
}

// async global->LDS, 16B per lane. LDS dest must be wave-base + lane*16 contiguous.
__device__ __forceinline__ void gload_lds16(const unsigned short* g, unsigned short* l) {
  __builtin_amdgcn_global_load_lds(
      (__attribute__((address_space(1))) const unsigned int*)g,
      (__attribute__((address_space(3))) unsigned int*)l, 16, 0, 0);
}

// ---------------- rope tables ----------------
__global__ __launch_bounds__(256) void rope_fill_kernel(float* __restrict__ c, float* __restrict__ s) {
  int i = blockIdx.x * 256 + threadIdx.x;
  if (i >= S_ * 32) return;
  int pos = i >> 5, j = i & 31;
  double inv = pow(10000.0, -(double)j / 32.0);
  double f = (double)pos * inv;
  c[i] = (float)cos(f);
  s[i] = (float)sin(f);
}

// ---------------- embedding gather ----------------
__global__ __launch_bounds__(256) void embed_kernel(const int* __restrict__ idx, const float* __restrict__ emb,
                                                    float* __restrict__ x) {
  int s = blockIdx.x, t = threadIdx.x;
  int row = idx[s];
  ((float4*)(x + (size_t)s * D_))[t] = ((const float4*)(emb + (size_t)row * D_))[t];
}

// ---------------- per-row quant stats (top-2 abs -> clip, scale, s16) ----------------
__global__ __launch_bounds__(256) void rowstats_kernel(const float* __restrict__ W, float4* __restrict__ qp,
                                                       int rows, int cols, float frac) {
  int gw = (int)((blockIdx.x * 256 + threadIdx.x) >> 6);
  int lane = threadIdx.x & 63;
  if (gw >= rows) return;
  const float* w = W + (size_t)gw * cols;
  float m1 = 0.f, m2 = 0.f;
  for (int c = lane; c < cols; c += 64) {
    float a = fabsf(w[c]);
    if (a > m1) { m2 = m1; m1 = a; }
    else if (a > m2) { m2 = a; }
  }
#pragma unroll
  for (int o = 32; o; o >>= 1) {
    float o1 = __shfl_xor(m1, o);
    float o2 = __shfl_xor(m2, o);
    float hi = fmaxf(m1, o1);
    float lo = fminf(m1, o1);
    m2 = fmaxf(lo, fmaxf(m2, o2));
    m1 = hi;
  }
  if (lane == 0) {
    float clip = m1 - (m1 - m2) * (1.0f - frac);   // numpy lerp form for t>=0.5
    float scale = fmaxf(clip / 127.0f, 1.0f / 127.0f);
    float s16 = __half2float(__float2half(scale));
    qp[gw] = make_float4(clip, scale, s16, 0.f);
  }
}

// ---------------- one-shot fake-quant fp32 -> bf16 (4 elems/thread) ----------------
__global__ __launch_bounds__(256) void quantw_kernel(const float* __restrict__ W, const float4* __restrict__ qp,
                                                     unsigned short* __restrict__ out, long nquad, int csh) {
  long i = (long)blockIdx.x * 256 + threadIdx.x;
  if (i >= nquad) return;
  int row = (int)(i >> (csh - 2));
  float4 q = qp[row];
  float4 w = ((const float4*)W)[i];
  ushort4 o;
  o.x = f2bf(fquant(w.x, q.x, q.y, q.z));
  o.y = f2bf(fquant(w.y, q.x, q.y, q.z));
  o.z = f2bf(fquant(w.z, q.x, q.y, q.z));
  o.w = f2bf(fquant(w.w, q.x, q.y, q.z));
  ((ushort4*)out)[i] = o;
}

// ---------------- rmsnorm over D=1024, fp32 in -> bf16 out ----------------
__global__ __launch_bounds__(256) void rmsnorm_kernel(const float* __restrict__ x, unsigned short* __restrict__ out) {
  __shared__ float red[4];
  int s = blockIdx.x, t = threadIdx.x;
  float4 v = ((const float4*)(x + (size_t)s * D_))[t];
  float ss = v.x * v.x + v.y * v.y + v.z * v.z + v.w * v.w;
#pragma unroll
  for (int o = 32; o; o >>= 1) ss += __shfl_xor(ss, o);
  if ((t & 63) == 0) red[t >> 6] = ss;
  __syncthreads();
  float tot = red[0] + red[1] + red[2] + red[3];
  float inv = 1.0f / sqrtf(tot * (1.0f / 1024.0f) + EPS_);
  ushort4 o4;
  o4.x = f2bf(v.x * inv); o4.y = f2bf(v.y * inv); o4.z = f2bf(v.z * inv); o4.w = f2bf(v.w * inv);
  ((ushort4*)(out + (size_t)s * D_))[t] = o4;
}

// ---------------- per-head rms + rope (+gain), fp32 in -> bf16 [nh][S][64] out ----------------
__global__ __launch_bounds__(256) void qkpost_kernel(const float* __restrict__ in, unsigned short* __restrict__ out,
                                                     const float* __restrict__ cosT, const float* __restrict__ sinT,
                                                     const float* __restrict__ gain, int nheads) {
  int gw = (int)((blockIdx.x * 256 + threadIdx.x) >> 6);
  int lane = threadIdx.x & 63;
  int s = gw / nheads;
  int h = gw - s * nheads;
  float v = in[(size_t)s * (nheads * 64) + h * 64 + lane];
  float ss = v * v;
#pragma unroll
  for (int o = 32; o; o >>= 1) ss += __shfl_xor(ss, o);
  v *= 1.0f / sqrtf(ss * (1.0f / 64.0f) + EPS_);
  float p = __shfl_xor(v, 32);
  int j = lane & 31;
  float c = cosT[s * 32 + j], sn = sinT[s * 32 + j];
  float o = v * c + ((lane < 32) ? p * sn : -p * sn);
  if (gain) o *= gain[h];
  out[((size_t)h * S_ + s) * 64 + lane] = f2bf(o);
}

// ---------------- pack V transposed: vT[kv][d][s] = v[s, kv*64+d], bf16 ----------------
__global__ __launch_bounds__(256) void vpack_kernel(const float* __restrict__ vbuf, unsigned short* __restrict__ vT) {
  int i = blockIdx.x * 256 + threadIdx.x;
  if (i >= S_ * 256) return;
  int s = i >> 8, c = i & 255;
  vT[(size_t)c * S_ + s] = f2bf(vbuf[i]);
}

// ---------------- causal softmax, single-pass: scores fp32 [H][S][S] -> probs bf16 ----------------
__global__ __launch_bounds__(256) void softmax_kernel(const float* __restrict__ scores, unsigned short* __restrict__ attnP) {
  int gw = (int)((blockIdx.x * 256 + threadIdx.x) >> 6);
  int lane = threadIdx.x & 63;
  int h = gw >> 10, s = gw & 1023;
  const float* row = scores + ((size_t)h * S_ + s) * S_;
  int nk = s + 1;
  float r[16];
  float m = -INFINITY;
#pragma unroll
  for (int i = 0; i < 16; i++) {
    int k = lane + i * 64;
    r[i] = (k < nk) ? row[k] : -INFINITY;
    m = fmaxf(m, r[i]);
  }
#pragma unroll
  for (int o = 32; o; o >>= 1) m = fmaxf(m, __shfl_xor(m, o));
  float sum = 0.f;
#pragma unroll
  for (int i = 0; i < 16; i++) {
    r[i] = expf(r[i] - m);   // exp(-inf)=0 for masked
    sum += r[i];
  }
#pragma unroll
  for (int o = 32; o; o >>= 1) sum += __shfl_xor(sum, o);
  float inv = 1.0f / sum;
  unsigned short* orow = attnP + ((size_t)h * S_ + s) * S_;
#pragma unroll
  for (int i = 0; i < 16; i++) {
    int k = lane + i * 64;
    orow[k] = f2bf(r[i] * inv);
  }
}

// ---------------- generic bf16 MFMA GEMM:  C[M,N] = alpha * A[M,K] * B[N,K]^T (+C) ----------------
// A, B bf16. EPI: 0 = fp32 store (ADD optional), 1 = bf16 store, 2 = relu^2 -> bf16 store.
// CAUSAL: 0 = none, 1 = skip tiles with n0 >= m0+BM (scores), 2 = truncate K at m0+BM (PV).
#define BM 128
#define BN 128
#define BK 64

template<int EPI, int ADD, int CAUSAL>
__global__ __launch_bounds__(256) void gemm_k(
    const unsigned short* __restrict__ A, long lda, long sA,
    const unsigned short* __restrict__ B, long ldb, long sB, int bzsh,
    void* __restrict__ Cp, long ldc, long sC,
    int N, int K, float alpha) {
  __shared__ alignas(16) unsigned short Alds[BM * BK];
  __shared__ alignas(16) unsigned short Blds[BN * BK];

  int m0 = blockIdx.y * BM, n0 = blockIdx.x * BN;
  if (CAUSAL == 1 && n0 >= m0 + BM) return;   // fully-masked score tile, never read
  int z = blockIdx.z;
  const unsigned short* Ab = A + (size_t)z * sA;
  const unsigned short* Bb = B + (size_t)(z >> bzsh) * sB;
  int tid = threadIdx.x;
  int wid = tid >> 6, lane = tid & 63;
  int wm = wid >> 1, wn = wid & 1;
  int quad = lane >> 4, r16 = lane & 15;

  int Keff = K;
  if (CAUSAL == 2) { int km = m0 + BM; if (km < Keff) Keff = km; }  // attnP == 0 beyond
  bool bfull = (n0 + BN <= N);

  floatx4 acc[4][4];
#pragma unroll
  for (int mi = 0; mi < 4; mi++)
#pragma unroll
    for (int ni = 0; ni < 4; ni++) acc[mi][ni] = (floatx4)0.0f;

  for (int kt = 0; kt < Keff; kt += BK) {
    // stage A via async global->LDS (M is always a multiple of BM)
#pragma unroll
    for (int i = 0; i < 4; i++) {
      int cc = tid + i * 256;
      int row = cc >> 3, kc = (cc & 7) * 8;
      gload_lds16(Ab + (size_t)(m0 + row) * lda + kt + kc, &Alds[cc * 8]);
    }
    // stage B
    if (bfull) {
#pragma unroll
      for (int i = 0; i < 4; i++) {
        int cc = tid + i * 256;
        int row = cc >> 3, kc = (cc & 7) * 8;
        gload_lds16(Bb + (size_t)(n0 + row) * ldb + kt + kc, &Blds[cc * 8]);
      }
    } else {
#pragma unroll
      for (int i = 0; i < 4; i++) {
        int cc = tid + i * 256;
        int row = cc >> 3, kc = (cc & 7) * 8;
        int n = n0 + row;
        uint4 v = {0, 0, 0, 0};
        if (n < N) v = *(const uint4*)(Bb + (size_t)n * ldb + kt + kc);
        *(uint4*)&Blds[cc * 8] = v;
      }
    }
    __syncthreads();

#pragma unroll
    for (int kk = 0; kk < BK; kk += 32) {
      short8 af[4], bfr[4];
#pragma unroll
      for (int mi = 0; mi < 4; mi++)
        af[mi] = *(const short8*)&Alds[(wm * 64 + mi * 16 + r16) * BK + kk + quad * 8];
#pragma unroll
      for (int ni = 0; ni < 4; ni++)
        bfr[ni] = *(const short8*)&Blds[(wn * 64 + ni * 16 + r16) * BK + kk + quad * 8];
#pragma unroll
      for (int mi = 0; mi < 4; mi++)
#pragma unroll
        for (int ni = 0; ni < 4; ni++)
          acc[mi][ni] = __builtin_amdgcn_mfma_f32_16x16x32_bf16(af[mi], bfr[ni], acc[mi][ni], 0, 0, 0);
    }
    __syncthreads();
  }

  // epilogue
  float* Cf = (float*)Cp + (size_t)z * sC;
  unsigned short* Cb = (unsigned short*)Cp + (size_t)z * sC;
#pragma unroll
  for (int mi = 0; mi < 4; mi++)
#pragma unroll
    for (int ni = 0; ni < 4; ni++) {
      int col = n0 + wn * 64 + ni * 16 + r16;
      if (col >= N) continue;
      long rowb = m0 + wm * 64 + mi * 16 + quad * 4;
#pragma unroll
      for (int r = 0; r < 4; r++) {
        long row = rowb + r;
        float v = acc[mi][ni][r] * alpha;
        if (EPI == 0) {
          float* ptr = Cf + row * ldc + col;
          if (ADD) v += *ptr;
          *ptr = v;
        } else if (EPI == 1) {
          Cb[row * ldc + col] = f2bf(v);
        } else {
          v = fmaxf(v, 0.0f);
          v = v * v;
          Cb[row * ldc + col] = f2bf(v);
        }
      }
    }
}

extern "C" void kernel_launch(void* const* d_in, const int* in_sizes, int n_in,
                              void* d_out, int out_size, void* d_ws, size_t ws_size,
                              hipStream_t stream) {
  const int* idx = (const int*)d_in[0];
  const float* emb = (const float*)d_in[1];
  const float* wq = (const float*)d_in[2];
  const float* wk = (const float*)d_in[3];
  const float* wv = (const float*)d_in[4];
  const float* wo = (const float*)d_in[5];
  const float* qg = (const float*)d_in[6];
  const float* wfc = (const float*)d_in[7];
  const float* wpr = (const float*)d_in[8];
  const float* lm = (const float*)d_in[9];
  float* out = (float*)d_out;

  char* p = (char*)d_ws;
  auto bump = [&](size_t bytes) { char* r = p; p += (bytes + 255) & ~(size_t)255; return r; };
  float* ropeC = (float*)bump((size_t)S_ * 32 * 4);
  float* ropeS = (float*)bump((size_t)S_ * 32 * 4);
  float4* qpWq = (float4*)bump((size_t)L_ * D_ * 16);
  float4* qpWk = (float4*)bump((size_t)L_ * 256 * 16);
  float4* qpWv = (float4*)bump((size_t)L_ * 256 * 16);
  float4* qpWo = (float4*)bump((size_t)L_ * D_ * 16);
  float4* qpFc = (float4*)bump((size_t)L_ * FF_ * 16);
  float4* qpPr = (float4*)bump((size_t)L_ * D_ * 16);
  float4* qpLm = (float4*)bump((size_t)V_ * 16);
  // bf16 pre-quantized weights (quantized once, reused by every GEMM tile pass)
  unsigned short* wqB = (unsigned short*)bump((size_t)L_ * D_ * D_ * 2);
  unsigned short* wkB = (unsigned short*)bump((size_t)L_ * 256 * D_ * 2);
  unsigned short* wvB = (unsigned short*)bump((size_t)L_ * 256 * D_ * 2);
  unsigned short* woB = (unsigned short*)bump((size_t)L_ * D_ * D_ * 2);
  unsigned short* wfcB = (unsigned short*)bump((size_t)L_ * FF_ * D_ * 2);
  unsigned short* wprB = (unsigned short*)bump((size_t)L_ * D_ * FF_ * 2);
  unsigned short* lmB = (unsigned short*)bump((size_t)V_ * D_ * 2);
  float* x = (float*)bump((size_t)S_ * D_ * 4);
  unsigned short* hbuf = (unsigned short*)bump((size_t)S_ * D_ * 2);
  float* qbuf = (float*)bump((size_t)S_ * D_ * 4);
  float* kbuf = (float*)bump((size_t)S_ * 256 * 4);
  float* vbuf = (float*)bump((size_t)S_ * 256 * 4);
  unsigned short* q_t = (unsigned short*)bump((size_t)H_ * S_ * 64 * 2);
  unsigned short* k_t = (unsigned short*)bump((size_t)KV_ * S_ * 64 * 2);
  unsigned short* vT = (unsigned short*)bump((size_t)KV_ * 64 * S_ * 2);
  float* scores = (float*)bump((size_t)H_ * S_ * S_ * 4);
  unsigned short* attnP = (unsigned short*)bump((size_t)H_ * S_ * S_ * 2);
  unsigned short* ybuf = (unsigned short*)bump((size_t)S_ * D_ * 2);
  unsigned short* ff = (unsigned short*)bump((size_t)S_ * FF_ * 2);

  float frac1024 = (float)((99.99984 / 100.0) * 1023.0 - 1022.0);
  float frac4096 = (float)((99.99984 / 100.0) * 4095.0 - 4094.0);

  rope_fill_kernel<<<(S_ * 32 + 255) / 256, 256, 0, stream>>>(ropeC, ropeS);
  embed_kernel<<<S_, 256, 0, stream>>>(idx, emb, x);
  rowstats_kernel<<<(L_ * D_ + 3) / 4, 256, 0, stream>>>(wq, qpWq, L_ * D_, 1024, frac1024);
  rowstats_kernel<<<(L_ * 256 + 3) / 4, 256, 0, stream>>>(wk, qpWk, L_ * 256, 1024, frac1024);
  rowstats_kernel<<<(L_ * 256 + 3) / 4, 256, 0, stream>>>(wv, qpWv, L_ * 256, 1024, frac1024);
  rowstats_kernel<<<(L_ * D_ + 3) / 4, 256, 0, stream>>>(wo, qpWo, L_ * D_, 1024, frac1024);
  rowstats_kernel<<<(L_ * FF_ + 3) / 4, 256, 0, stream>>>(wfc, qpFc, L_ * FF_, 1024, frac1024);
  rowstats_kernel<<<(L_ * D_ + 3) / 4, 256, 0, stream>>>(wpr, qpPr, L_ * D_, 4096, frac4096);
  rowstats_kernel<<<(V_ + 3) / 4, 256, 0, stream>>>(lm, qpLm, V_, 1024, frac1024);

  auto qlaunch = [&](const float* W, float4* qp, unsigned short* o, long rows, int csh) {
    long nq = (rows << csh) >> 2;
    quantw_kernel<<<(int)((nq + 255) / 256), 256, 0, stream>>>(W, qp, o, nq, csh);
  };
  qlaunch(wq, qpWq, wqB, L_ * D_, 10);
  qlaunch(wk, qpWk, wkB, L_ * 256, 10);
  qlaunch(wv, qpWv, wvB, L_ * 256, 10);
  qlaunch(wo, qpWo, woB, L_ * D_, 10);
  qlaunch(wfc, qpFc, wfcB, L_ * FF_, 10);
  qlaunch(wpr, qpPr, wprB, L_ * D_, 12);
  qlaunch(lm, qpLm, lmB, V_, 10);

  for (int l = 0; l < L_; l++) {
    rmsnorm_kernel<<<S_, 256, 0, stream>>>(x, hbuf);
    gemm_k<0, 0, 0><<<dim3(8, 8, 1), 256, 0, stream>>>(hbuf, D_, 0, wqB + (size_t)l * D_ * D_, D_, 0, 0,
                                                       qbuf, D_, 0, D_, D_, 1.0f);
    gemm_k<0, 0, 0><<<dim3(2, 8, 1), 256, 0, stream>>>(hbuf, D_, 0, wkB + (size_t)l * 256 * D_, D_, 0, 0,
                                                       kbuf, 256, 0, 256, D_, 1.0f);
    gemm_k<0, 0, 0><<<dim3(2, 8, 1), 256, 0, stream>>>(hbuf, D_, 0, wvB + (size_t)l * 256 * D_, D_, 0, 0,
                                                       vbuf, 256, 0, 256, D_, 1.0f);
    qkpost_kernel<<<S_ * H_ / 4, 256, 0, stream>>>(qbuf, q_t, ropeC, ropeS, qg + l * H_, H_);
    qkpost_kernel<<<S_ * KV_ / 4, 256, 0, stream>>>(kbuf, k_t, ropeC, ropeS, nullptr, KV_);
    vpack_kernel<<<S_ * 256 / 256, 256, 0, stream>>>(vbuf, vT);
    gemm_k<0, 0, 1><<<dim3(8, 8, 16), 256, 0, stream>>>(q_t, 64, (long)S_ * 64, k_t, 64, (long)S_ * 64, 2,
                                                        scores, S_, (long)S_ * S_, S_, 64, 0.125f);
    softmax_kernel<<<H_ * S_ / 4, 256, 0, stream>>>(scores, attnP);
    gemm_k<1, 0, 2><<<dim3(1, 8, 16), 256, 0, stream>>>(attnP, S_, (long)S_ * S_, vT, S_, (long)64 * S_, 2,
                                                        ybuf, D_, 64, 64, S_, 1.0f);
    gemm_k<0, 1, 0><<<dim3(8, 8, 1), 256, 0, stream>>>(ybuf, D_, 0, woB + (size_t)l * D_ * D_, D_, 0, 0,
                                                       x, D_, 0, D_, D_, 1.0f);
    rmsnorm_kernel<<<S_, 256, 0, stream>>>(x, hbuf);
    gemm_k<2, 0, 0><<<dim3(32, 8, 1), 256, 0, stream>>>(hbuf, D_, 0, wfcB + (size_t)l * FF_ * D_, D_, 0, 0,
                                                        ff, FF_, 0, FF_, D_, 1.0f);
    gemm_k<0, 1, 0><<<dim3(8, 8, 1), 256, 0, stream>>>(ff, FF_, 0, wprB + (size_t)l * D_ * FF_, FF_, 0, 0,
                                                       x, D_, 0, D_, FF_, 1.0f);
  }
  rmsnorm_kernel<<<S_, 256, 0, stream>>>(x, hbuf);
  gemm_k<0, 0, 0><<<dim3((V_ + 127) / 128, 8, 1), 256, 0, stream>>>(hbuf, D_, 0, lmB, D_, 0, 0,
                                                                    out, V_, 0, V_, D_, 1.0f);
}